// Round 2
// baseline (41.141 us; speedup 1.0000x reference)
//
#include <hip/hip_runtime.h>
#include <math.h>

// BBoxEstimatorLoss: fused per-sample loss + deterministic 2-stage reduction.
// BS = 524288. R1: 2 samples/thread, load-first structure, register selects
// for score gathers, reciprocal table instead of divides.
// 1024 blocks x 256 threads x 2 samples = 524288.

constexpr int BS_N = 524288;
constexpr int NBLK = 1024;

__constant__ float G_MEAN[8][3] = {
    {3.88f, 1.63f, 1.53f}, {0.84f, 0.66f, 1.76f}, {1.76f, 0.60f, 1.74f},
    {16.17f, 2.58f, 3.23f}, {3.90f, 1.60f, 1.56f}, {1.73f, 0.58f, 1.37f},
    {0.91f, 0.48f, 1.78f}, {2.06f, 1.86f, 1.66f}
};
__constant__ float G_RCP[8][3] = {
    {1.0f/3.88f, 1.0f/1.63f, 1.0f/1.53f}, {1.0f/0.84f, 1.0f/0.66f, 1.0f/1.76f},
    {1.0f/1.76f, 1.0f/0.60f, 1.0f/1.74f}, {1.0f/16.17f, 1.0f/2.58f, 1.0f/3.23f},
    {1.0f/3.90f, 1.0f/1.60f, 1.0f/1.56f}, {1.0f/1.73f, 1.0f/0.58f, 1.0f/1.37f},
    {1.0f/0.91f, 1.0f/0.48f, 1.0f/1.78f}, {1.0f/2.06f, 1.0f/1.86f, 1.0f/1.66f}
};

__device__ __forceinline__ float huber_pos(float a, float delta) {
    return (a <= delta) ? 0.5f * a * a : delta * (a - 0.5f * delta);
}
__device__ __forceinline__ float huber_norm2(float d2, float delta) {
    return (d2 <= delta * delta) ? 0.5f * d2
                                 : delta * (sqrtf(d2) - 0.5f * delta);
}
// register-select element k of a float4 (cndmask chain, no memory)
__device__ __forceinline__ float sel4(float4 v, int k) {
    float r = v.x;
    r = (k == 1) ? v.y : r;
    r = (k == 2) ? v.z : r;
    r = (k == 3) ? v.w : r;
    return r;
}
__device__ __forceinline__ float sel12(float4 a, float4 b, float4 c, int k) {
    float r = sel4(a, k);
    r = (k >= 4) ? sel4(b, k - 4) : r;
    r = (k >= 8) ? sel4(c, k - 8) : r;
    return r;
}
__device__ __forceinline__ float sel8(float4 a, float4 b, int k) {
    float r = sel4(a, k);
    r = (k >= 4) ? sel4(b, k - 4) : r;
    return r;
}

__device__ __forceinline__ float sample_loss(
    int h, int s,
    float cx, float cy, float cz,       // center
    float lx, float ly, float lz,       // center_label
    float tx, float ty, float tz,       // stage1_center
    float4 hsA, float4 hsB, float4 hsC, // heading_scores row
    float4 ssA, float4 ssB,             // size_scores row
    float hrl,                          // heading_residuals_label
    float hrnv, float hrev,             // hrn[.,h], hres[.,h]
    float sl0, float sl1, float sl2,    // size_residuals_label
    float sn0, float sn1, float sn2,    // srn[.,s,:]
    float sr0, float sr1, float sr2)    // sres[.,s,:]
{
    float contrib = 0.0f;

    const float dx0 = cx - lx, dy0 = cy - ly, dz0 = cz - lz;
    contrib += huber_norm2(dx0*dx0 + dy0*dy0 + dz0*dz0, 2.0f);       // center_loss
    {
        const float ax = cx - tx, ay = cy - ty, az = cz - tz;
        contrib += huber_norm2(ax*ax + ay*ay + az*az, 1.0f);         // stage1_center_loss
    }

    // heading log-softmax (12)
    {
        float m = fmaxf(fmaxf(fmaxf(hsA.x,hsA.y),fmaxf(hsA.z,hsA.w)),
                  fmaxf(fmaxf(fmaxf(hsB.x,hsB.y),fmaxf(hsB.z,hsB.w)),
                        fmaxf(fmaxf(hsC.x,hsC.y),fmaxf(hsC.z,hsC.w))));
        float se = __expf(hsA.x-m)+__expf(hsA.y-m)+__expf(hsA.z-m)+__expf(hsA.w-m)
                 + __expf(hsB.x-m)+__expf(hsB.y-m)+__expf(hsB.z-m)+__expf(hsB.w-m)
                 + __expf(hsC.x-m)+__expf(hsC.y-m)+__expf(hsC.z-m)+__expf(hsC.w-m);
        contrib += m + __logf(se) - sel12(hsA, hsB, hsC, h);         // heading_class_loss
    }
    // size log-softmax (8)
    {
        float m = fmaxf(fmaxf(fmaxf(ssA.x,ssA.y),fmaxf(ssA.z,ssA.w)),
                        fmaxf(fmaxf(ssB.x,ssB.y),fmaxf(ssB.z,ssB.w)));
        float se = __expf(ssA.x-m)+__expf(ssA.y-m)+__expf(ssA.z-m)+__expf(ssA.w-m)
                 + __expf(ssB.x-m)+__expf(ssB.y-m)+__expf(ssB.z-m)+__expf(ssB.w-m);
        contrib += m + __logf(se) - sel8(ssA, ssB, s);               // size_class_loss
    }

    // heading residual loss (x20)
    contrib += 20.0f * huber_pos(fabsf(hrnv - hrl * (float)(12.0 / M_PI)), 1.0f);

    // size residual loss (x20)
    const float m0 = G_MEAN[s][0], m1 = G_MEAN[s][1], m2c = G_MEAN[s][2];
    {
        const float e0 = sl0 * G_RCP[s][0] - sn0;
        const float e1 = sl1 * G_RCP[s][1] - sn1;
        const float e2 = sl2 * G_RCP[s][2] - sn2;
        contrib += 20.0f * huber_norm2(e0*e0 + e1*e1 + e2*e2, 1.0f);
    }

    // corner loss (x10, mean over 8 corners)
    {
        const float binc = (float)h * (float)(M_PI / 6.0);
        const float hp = hrev + binc;                 // heading_pred
        const float hg = hrl + binc;                  // heading_label
        const float lp2 = 0.5f * (m0 + sr0);
        const float wp2 = 0.5f * (m1 + sr1);
        const float hp2 = 0.5f * (m2c + sr2);
        const float lg2 = 0.5f * (m0 + sl0);
        const float wg2 = 0.5f * (m1 + sl1);
        const float hg2 = 0.5f * (m2c + sl2);
        float cp, sp, cg, sg;
        __sincosf(hp, &sp, &cp);
        __sincosf(hg, &sg, &cg);
        const float dyh = hp2 - hg2;

        constexpr float SX[8] = {1,1,-1,-1,1,1,-1,-1};
        constexpr float SY[8] = {1,1,1,1,-1,-1,-1,-1};
        constexpr float SZ[8] = {1,-1,-1,1,1,-1,-1,1};
        float csum = 0.0f;
        #pragma unroll
        for (int j = 0; j < 8; ++j) {
            const float axp = SX[j]*lp2, azp = SZ[j]*wp2;
            const float xrp = cp*axp + sp*azp;
            const float zrp = cp*azp - sp*axp;
            const float axg = SX[j]*lg2, azg = SZ[j]*wg2;
            const float xrg = cg*axg + sg*azg;
            const float zrg = cg*azg - sg*axg;
            const float ddy = dy0 + SY[j]*dyh;
            const float u = dx0 + xrp, v = dz0 + zrp;
            const float du1 = u - xrg, dv1 = v - zrg;   // vs gt
            const float du2 = u + xrg, dv2 = v + zrg;   // vs gt_flip (heading+pi)
            const float y2 = ddy*ddy;
            const float dgt = du1*du1 + y2 + dv1*dv1;
            const float dfl = du2*du2 + y2 + dv2*dv2;
            const float mm = fminf(dgt, dfl);
            csum += (mm <= 1.0f) ? 0.5f*mm : sqrtf(mm) - 0.5f;
        }
        contrib += 1.25f * csum;   // 10.0 * (1/8)
    }
    return contrib;
}

__global__ __launch_bounds__(256) void bbox_partial(
    const float* __restrict__ center,
    const float* __restrict__ center_label,
    const float* __restrict__ stage1_center,
    const float* __restrict__ heading_scores,
    const float* __restrict__ hrn,
    const float* __restrict__ hres,
    const int*   __restrict__ hcls_in,
    const float* __restrict__ hres_label,
    const float* __restrict__ size_scores,
    const float* __restrict__ srn,
    const float* __restrict__ sres,
    const int*   __restrict__ scls_in,
    const float* __restrict__ sres_label,
    float* __restrict__ block_out)
{
    const int t  = blockIdx.x * 256 + threadIdx.x;
    const int i0 = 2 * t;

    // ===== phase 1: issue ALL loads =====
    // indices first (gathers depend on them)
    const int2 h2 = *reinterpret_cast<const int2*>(hcls_in + i0);
    const int2 s2 = *reinterpret_cast<const int2*>(scls_in + i0);

    // bulk vector loads (independent of indices)
    const float2* cp2 = reinterpret_cast<const float2*>(center        + 3*i0);
    const float2* lp2 = reinterpret_cast<const float2*>(center_label  + 3*i0);
    const float2* tp2 = reinterpret_cast<const float2*>(stage1_center + 3*i0);
    const float2* rp2 = reinterpret_cast<const float2*>(sres_label    + 3*i0);
    const float2 cA = cp2[0], cB = cp2[1], cC = cp2[2];
    const float2 lA = lp2[0], lB = lp2[1], lC = lp2[2];
    const float2 tA = tp2[0], tB = tp2[1], tC = tp2[2];
    const float2 rA = rp2[0], rB = rp2[1], rC = rp2[2];
    const float2 hl = *reinterpret_cast<const float2*>(hres_label + i0);

    const float4* hsp = reinterpret_cast<const float4*>(heading_scores + 12*i0);
    const float4 hsA0 = hsp[0], hsB0 = hsp[1], hsC0 = hsp[2];
    const float4 hsA1 = hsp[3], hsB1 = hsp[4], hsC1 = hsp[5];
    const float4* ssp = reinterpret_cast<const float4*>(size_scores + 8*i0);
    const float4 ssA0 = ssp[0], ssB0 = ssp[1];
    const float4 ssA1 = ssp[2], ssB1 = ssp[3];

    // dependent gathers (one round trip after h/s arrive)
    const int h0 = h2.x, h1 = h2.y, s0 = s2.x, s1 = s2.y;
    const float hrn0 = hrn [12*i0 + h0],      hrn1 = hrn [12*i0 + 12 + h1];
    const float hre0 = hres[12*i0 + h0],      hre1 = hres[12*i0 + 12 + h1];
    const int sb0 = (8*i0 + s0) * 3,          sb1 = (8*i0 + 8 + s1) * 3;
    const float sn00 = srn [sb0+0], sn01 = srn [sb0+1], sn02 = srn [sb0+2];
    const float sn10 = srn [sb1+0], sn11 = srn [sb1+1], sn12 = srn [sb1+2];
    const float sr00 = sres[sb0+0], sr01 = sres[sb0+1], sr02 = sres[sb0+2];
    const float sr10 = sres[sb1+0], sr11 = sres[sb1+1], sr12 = sres[sb1+2];

    // ===== phase 2: compute =====
    float contrib =
        sample_loss(h0, s0,
                    cA.x, cA.y, cB.x,  lA.x, lA.y, lB.x,  tA.x, tA.y, tB.x,
                    hsA0, hsB0, hsC0,  ssA0, ssB0,
                    hl.x, hrn0, hre0,
                    rA.x, rA.y, rB.x,
                    sn00, sn01, sn02,  sr00, sr01, sr02)
      + sample_loss(h1, s1,
                    cB.y, cC.x, cC.y,  lB.y, lC.x, lC.y,  tB.y, tC.x, tC.y,
                    hsA1, hsB1, hsC1,  ssA1, ssB1,
                    hl.y, hrn1, hre1,
                    rB.y, rC.x, rC.y,
                    sn10, sn11, sn12,  sr10, sr11, sr12);

    // ===== deterministic block reduction =====
    #pragma unroll
    for (int off = 32; off > 0; off >>= 1)
        contrib += __shfl_down(contrib, off, 64);

    __shared__ float sdata[4];
    const int lane = threadIdx.x & 63;
    const int wid  = threadIdx.x >> 6;
    if (lane == 0) sdata[wid] = contrib;
    __syncthreads();
    if (threadIdx.x == 0)
        block_out[blockIdx.x] = (sdata[0] + sdata[1]) + (sdata[2] + sdata[3]);
}

__global__ __launch_bounds__(256) void bbox_final(
    const float* __restrict__ block_in, float* __restrict__ out)
{
    float ssum = 0.0f;
    for (int i = threadIdx.x; i < NBLK; i += 256)
        ssum += block_in[i];
    #pragma unroll
    for (int off = 32; off > 0; off >>= 1)
        ssum += __shfl_down(ssum, off, 64);

    __shared__ float sdata[4];
    const int lane = threadIdx.x & 63;
    const int wid  = threadIdx.x >> 6;
    if (lane == 0) sdata[wid] = ssum;
    __syncthreads();
    if (threadIdx.x == 0)
        out[0] = ((sdata[0] + sdata[1]) + (sdata[2] + sdata[3])) * (1.0f / (float)BS_N);
}

extern "C" void kernel_launch(void* const* d_in, const int* in_sizes, int n_in,
                              void* d_out, int out_size, void* d_ws, size_t ws_size,
                              hipStream_t stream) {
    const float* center        = (const float*)d_in[0];
    const float* center_label  = (const float*)d_in[1];
    const float* stage1_center = (const float*)d_in[2];
    const float* heading_sc    = (const float*)d_in[3];
    const float* hrn           = (const float*)d_in[4];
    const float* hres          = (const float*)d_in[5];
    const int*   hcls          = (const int*)d_in[6];
    const float* hres_label    = (const float*)d_in[7];
    const float* size_sc       = (const float*)d_in[8];
    const float* srn           = (const float*)d_in[9];
    const float* sres          = (const float*)d_in[10];
    const int*   scls          = (const int*)d_in[11];
    const float* sres_label    = (const float*)d_in[12];

    float* ws  = (float*)d_ws;     // NBLK partial sums (4 KiB)
    float* out = (float*)d_out;

    bbox_partial<<<NBLK, 256, 0, stream>>>(
        center, center_label, stage1_center, heading_sc, hrn, hres,
        hcls, hres_label, size_sc, srn, sres, scls, sres_label, ws);
    bbox_final<<<1, 256, 0, stream>>>(ws, out);
}